// Round 1
// baseline (90.121 us; speedup 1.0000x reference)
//
#include <hip/hip_runtime.h>
#include <stdint.h>

#define BTOT 4096
#define DD   256
#define SS   32
#define KKN  32

typedef unsigned short u16;
using f32x4  = __attribute__((ext_vector_type(4))) float;
using bf16x8 = __attribute__((ext_vector_type(8))) short;

__device__ __forceinline__ u16 f2bf(float f) {
    uint32_t u = __builtin_bit_cast(uint32_t, f);
    u = (u + 0x7FFFu + ((u >> 16) & 1u)) >> 16;
    return (u16)u;
}
__device__ __forceinline__ float bf2f(u16 h) {
    uint32_t u = ((uint32_t)h) << 16;
    return __builtin_bit_cast(float, u);
}

// ---- kernel 0: cast embeddings fp32 -> bf16 (8 elems/thread) ----
__global__ __launch_bounds__(256) void cast_kernel(const float* __restrict__ E,
                                                   u16* __restrict__ ebf) {
    int idx = blockIdx.x * 256 + threadIdx.x;
    const float4* p = reinterpret_cast<const float4*>(E) + (size_t)idx * 2;
    float4 a = p[0], b = p[1];
    uint4 o;
    o.x = (uint32_t)f2bf(a.x) | ((uint32_t)f2bf(a.y) << 16);
    o.y = (uint32_t)f2bf(a.z) | ((uint32_t)f2bf(a.w) << 16);
    o.z = (uint32_t)f2bf(b.x) | ((uint32_t)f2bf(b.y) << 16);
    o.w = (uint32_t)f2bf(b.z) | ((uint32_t)f2bf(b.w) << 16);
    reinterpret_cast<uint4*>(ebf)[idx] = o;
}

// ---- kernel 1: fused E@E^T (bf16 MFMA) + per-row exp-sum / masked-sum ----
// 128x128 tile, BK=32, 4 waves (2x2 of 64x64), m97-style global_load_lds staging.
__global__ __launch_bounds__(256) void gemm_reduce_kernel(
    const u16* __restrict__ ebf, const int* __restrict__ labels,
    float* __restrict__ acc_den, float* __restrict__ acc_num)
{
    __shared__ u16 As[128 * 32];
    __shared__ u16 Bs[128 * 32];

    int bid  = blockIdx.x;
    int brow = (bid >> 5) * 128;
    int bcol = (bid & 31) * 128;
    int t    = threadIdx.x;
    int w    = t >> 6;
    int lane = t & 63;
    int wr   = w >> 1, wc = w & 1;
    int r16  = lane & 15;
    int kq   = (lane >> 4) * 8;

    f32x4 acc[4][4] = {};

    for (int kt = 0; kt < DD / 32; ++kt) {
        int k0 = kt * 32;
        #pragma unroll
        for (int it = 0; it < 2; ++it) {
            int c   = t + 256 * it;
            int row = c >> 2;          // 4 chunks of 8 bf16 per 32-wide row
            int col = (c & 3) * 8;
            const u16* ga = &ebf[(size_t)(brow + row) * DD + k0 + col];
            const u16* gb = &ebf[(size_t)(bcol + row) * DD + k0 + col];
            __builtin_amdgcn_global_load_lds(
                (const __attribute__((address_space(1))) unsigned int*)ga,
                (__attribute__((address_space(3))) unsigned int*)&As[c * 8], 16, 0, 0);
            __builtin_amdgcn_global_load_lds(
                (const __attribute__((address_space(1))) unsigned int*)gb,
                (__attribute__((address_space(3))) unsigned int*)&Bs[c * 8], 16, 0, 0);
        }
        __syncthreads();

        bf16x8 af[4], bfr[4];
        #pragma unroll
        for (int m = 0; m < 4; ++m)
            af[m] = *(const bf16x8*)&As[(wr * 64 + m * 16 + r16) * 32 + kq];
        #pragma unroll
        for (int n = 0; n < 4; ++n)
            bfr[n] = *(const bf16x8*)&Bs[(wc * 64 + n * 16 + r16) * 32 + kq];
        #pragma unroll
        for (int m = 0; m < 4; ++m)
            #pragma unroll
            for (int n = 0; n < 4; ++n)
                acc[m][n] = __builtin_amdgcn_mfma_f32_16x16x32_bf16(af[m], bfr[n], acc[m][n], 0, 0, 0);
        __syncthreads();
    }

    // epilogue: per-row partial reductions. C map: col=lane&15, row=(lane>>4)*4+r.
    float malf[4];
    #pragma unroll
    for (int n = 0; n < 4; ++n)
        malf[n] = (float)labels[bcol + wc * 64 + n * 16 + r16];

    int rowbase = brow + wr * 64 + (lane >> 4) * 4;
    #pragma unroll
    for (int m = 0; m < 4; ++m) {
        #pragma unroll
        for (int r = 0; r < 4; ++r) {
            float pe = 0.f, pn = 0.f;
            #pragma unroll
            for (int n = 0; n < 4; ++n) {
                float v = acc[m][n][r];
                pe += __expf(v);
                pn += malf[n] * v;
            }
            #pragma unroll
            for (int s = 1; s < 16; s <<= 1) {
                pe += __shfl_xor(pe, s, 64);
                pn += __shfl_xor(pn, s, 64);
            }
            if (r16 == 0) {
                int i = rowbase + m * 16 + r;
                atomicAdd(&acc_den[i], pe);
                atomicAdd(&acc_num[i], pn);
            }
        }
    }
}

// ---- kernel 2: similar/diverse dots (streaming, memory-bound) + self-term fix ----
__global__ __launch_bounds__(256) void simdiv_kernel(
    const float* __restrict__ E, const float* __restrict__ Sim, const float* __restrict__ Div,
    const u16* __restrict__ ebf, const int* __restrict__ labels,
    float* __restrict__ acc_den, float* __restrict__ acc_num)
{
    int i = blockIdx.x;
    int t = threadIdx.x, w = t >> 6, lane = t & 63;

    float4 e4 = reinterpret_cast<const float4*>(E + (size_t)i * DD)[lane];

    float lsum = 0.f, lexp = 0.f;
    for (int vt = 0; vt < 16; ++vt) {
        int v = w * 16 + vt;
        const float* src = (v < SS) ? (Sim + ((size_t)i * SS + v) * DD)
                                    : (Div + ((size_t)i * KKN + (v - SS)) * DD);
        float4 s4 = reinterpret_cast<const float4*>(src)[lane];
        float d = e4.x * s4.x + e4.y * s4.y + e4.z * s4.z + e4.w * s4.w;
        #pragma unroll
        for (int sh = 1; sh < 64; sh <<= 1) d += __shfl_xor(d, sh, 64);
        if (lane == 0) { lsum += d; lexp += __expf(d); }
    }

    // wave 0 also computes the bf16 self-dot (matches MFMA diagonal) and corrections
    if (w == 0) {
        uint2 q = reinterpret_cast<const uint2*>(ebf + (size_t)i * DD)[lane];
        float a0 = bf2f((u16)(q.x & 0xFFFF)), a1 = bf2f((u16)(q.x >> 16));
        float a2 = bf2f((u16)(q.y & 0xFFFF)), a3 = bf2f((u16)(q.y >> 16));
        float sd = a0 * a0 + a1 * a1 + a2 * a2 + a3 * a3;
        #pragma unroll
        for (int sh = 1; sh < 64; sh <<= 1) sd += __shfl_xor(sd, sh, 64);
        if (lane == 0) {
            lexp -= __expf(sd);                    // remove j==i from denominator
            lsum -= (float)labels[i] * sd;         // remove j==i from numerator if mal[i]
        }
    }
    if (lane == 0) {
        atomicAdd(&acc_num[i], lsum);
        atomicAdd(&acc_den[i], lexp);
    }
}

// ---- kernel 3: final per-row loss + scalar reduce ----
__global__ __launch_bounds__(256) void final_kernel(
    const int* __restrict__ labels, const float* __restrict__ acc_den,
    const float* __restrict__ acc_num, float* __restrict__ out)
{
    __shared__ int   ibuf[256];
    __shared__ float sbuf[256];
    int t = threadIdx.x;

    int mt = 0;
    for (int it = 0; it < BTOT / 256; ++it) mt += labels[t + it * 256];
    ibuf[t] = mt; __syncthreads();
    for (int s = 128; s > 0; s >>= 1) { if (t < s) ibuf[t] += ibuf[t + s]; __syncthreads(); }
    int mal_total = ibuf[0];
    float cnt = (float)(mal_total - 1 + SS + KKN);

    float total = 0.f;
    for (int it = 0; it < BTOT / 256; ++it) {
        int i = t + it * 256;
        if (labels[i]) total += -acc_num[i] / cnt + __logf(acc_den[i]);
    }
    sbuf[t] = total; __syncthreads();
    for (int s = 128; s > 0; s >>= 1) { if (t < s) sbuf[t] += sbuf[t + s]; __syncthreads(); }
    if (t == 0) out[0] = sbuf[0] / (float)BTOT;
}

extern "C" void kernel_launch(void* const* d_in, const int* in_sizes, int n_in,
                              void* d_out, int out_size, void* d_ws, size_t ws_size,
                              hipStream_t stream) {
    const float* E   = (const float*)d_in[0];
    const float* Sim = (const float*)d_in[1];
    const float* Div = (const float*)d_in[2];
    const int* labels = (const int*)d_in[3];
    float* out = (float*)d_out;

    u16*   ebf     = (u16*)d_ws;
    float* acc_den = (float*)((char*)d_ws + (size_t)BTOT * DD * sizeof(u16));
    float* acc_num = acc_den + BTOT;

    hipMemsetAsync(acc_den, 0, 2 * BTOT * sizeof(float), stream);
    cast_kernel<<<BTOT * DD / 8 / 256, 256, 0, stream>>>(E, ebf);
    gemm_reduce_kernel<<<dim3((BTOT / 128) * (BTOT / 128)), 256, 0, stream>>>(ebf, labels, acc_den, acc_num);
    simdiv_kernel<<<BTOT, 256, 0, stream>>>(E, Sim, Div, ebf, labels, acc_den, acc_num);
    final_kernel<<<1, 256, 0, stream>>>(labels, acc_den, acc_num, out);
}

// Round 2
// 84.016 us; speedup vs baseline: 1.0727x; 1.0727x over previous
//
#include <hip/hip_runtime.h>
#include <stdint.h>

#define BTOT 4096
#define DD   256
#define SS   32
#define KKN  32

typedef unsigned short u16;
using f32x4  = __attribute__((ext_vector_type(4))) float;
using bf16x8 = __attribute__((ext_vector_type(8))) short;

__device__ __forceinline__ u16 f2bf(float f) {
    uint32_t u = __builtin_bit_cast(uint32_t, f);
    u = (u + 0x7FFFu + ((u >> 16) & 1u)) >> 16;
    return (u16)u;
}
__device__ __forceinline__ float bf2f(u16 h) {
    uint32_t u = ((uint32_t)h) << 16;
    return __builtin_bit_cast(float, u);
}

// ---- kernel 0: cast embeddings fp32 -> bf16 (8 elems/thread) ----
__global__ __launch_bounds__(256) void cast_kernel(const float* __restrict__ E,
                                                   u16* __restrict__ ebf) {
    int idx = blockIdx.x * 256 + threadIdx.x;
    const float4* p = reinterpret_cast<const float4*>(E) + (size_t)idx * 2;
    float4 a = p[0], b = p[1];
    uint4 o;
    o.x = (uint32_t)f2bf(a.x) | ((uint32_t)f2bf(a.y) << 16);
    o.y = (uint32_t)f2bf(a.z) | ((uint32_t)f2bf(a.w) << 16);
    o.z = (uint32_t)f2bf(b.x) | ((uint32_t)f2bf(b.y) << 16);
    o.w = (uint32_t)f2bf(b.z) | ((uint32_t)f2bf(b.w) << 16);
    reinterpret_cast<uint4*>(ebf)[idx] = o;
}

// ---- fat kernel: even blocks = GEMM tile, odd blocks = simdiv rows ----
__global__ __launch_bounds__(256) void fat_kernel(
    const float* __restrict__ E, const float* __restrict__ Sim, const float* __restrict__ Div,
    const u16* __restrict__ ebf, const int* __restrict__ labels,
    float* __restrict__ acc_den, float* __restrict__ acc_num)
{
    __shared__ u16 As[128 * 32];
    __shared__ u16 Bs[128 * 32];

    int bid  = blockIdx.x;
    int t    = threadIdx.x;
    int w    = t >> 6;
    int lane = t & 63;

    if ((bid & 1) == 0) {
        // ================= GEMM path =================
        int tid  = bid >> 1;
        int brow = (tid >> 5) * 128;
        int bcol = (tid & 31) * 128;
        int wr   = w >> 1, wc = w & 1;
        int r16  = lane & 15;
        int kq   = (lane >> 4) * 8;

        f32x4 acc[4][4] = {};

        for (int kt = 0; kt < DD / 32; ++kt) {
            int k0 = kt * 32;
            #pragma unroll
            for (int it = 0; it < 2; ++it) {
                int c   = t + 256 * it;
                int row = c >> 2;
                int col = (c & 3) * 8;
                const u16* ga = &ebf[(size_t)(brow + row) * DD + k0 + col];
                const u16* gb = &ebf[(size_t)(bcol + row) * DD + k0 + col];
                __builtin_amdgcn_global_load_lds(
                    (const __attribute__((address_space(1))) unsigned int*)ga,
                    (__attribute__((address_space(3))) unsigned int*)&As[c * 8], 16, 0, 0);
                __builtin_amdgcn_global_load_lds(
                    (const __attribute__((address_space(1))) unsigned int*)gb,
                    (__attribute__((address_space(3))) unsigned int*)&Bs[c * 8], 16, 0, 0);
            }
            __syncthreads();

            bf16x8 af[4], bfr[4];
            #pragma unroll
            for (int m = 0; m < 4; ++m)
                af[m] = *(const bf16x8*)&As[(wr * 64 + m * 16 + r16) * 32 + kq];
            #pragma unroll
            for (int n = 0; n < 4; ++n)
                bfr[n] = *(const bf16x8*)&Bs[(wc * 64 + n * 16 + r16) * 32 + kq];
            #pragma unroll
            for (int m = 0; m < 4; ++m)
                #pragma unroll
                for (int n = 0; n < 4; ++n)
                    acc[m][n] = __builtin_amdgcn_mfma_f32_16x16x32_bf16(af[m], bfr[n], acc[m][n], 0, 0, 0);
            __syncthreads();
        }

        float malf[4];
        #pragma unroll
        for (int n = 0; n < 4; ++n)
            malf[n] = (float)labels[bcol + wc * 64 + n * 16 + r16];

        int rowbase = brow + wr * 64 + (lane >> 4) * 4;
        #pragma unroll
        for (int m = 0; m < 4; ++m) {
            #pragma unroll
            for (int r = 0; r < 4; ++r) {
                float pe = 0.f, pn = 0.f;
                #pragma unroll
                for (int n = 0; n < 4; ++n) {
                    float v = acc[m][n][r];
                    pe += __expf(v);
                    pn += malf[n] * v;
                }
                #pragma unroll
                for (int s = 1; s < 16; s <<= 1) {
                    pe += __shfl_xor(pe, s, 64);
                    pn += __shfl_xor(pn, s, 64);
                }
                if (r16 == 0) {
                    int i = rowbase + m * 16 + r;
                    atomicAdd(&acc_den[i], pe);
                    atomicAdd(&acc_num[i], pn);
                }
            }
        }
    } else {
        // ================= simdiv path =================
        int i   = (bid >> 1) * 4 + w;     // one row per wave
        int g   = lane >> 4;              // 4 groups of 16 lanes
        int sub = lane & 15;

        const float4* Ei = reinterpret_cast<const float4*>(E + (size_t)i * DD);
        float4 e[4];
        #pragma unroll
        for (int p = 0; p < 4; ++p) e[p] = Ei[p * 16 + sub];

        float accs = 0.f, acce = 0.f;
        #pragma unroll 2
        for (int vt = 0; vt < 16; ++vt) {
            int v = vt * 4 + g;
            const float* src = (v < SS) ? (Sim + ((size_t)i * SS + v) * DD)
                                        : (Div + ((size_t)i * KKN + (v - SS)) * DD);
            const float4* s4p = reinterpret_cast<const float4*>(src);
            float4 s0 = s4p[0 * 16 + sub];
            float4 s1 = s4p[1 * 16 + sub];
            float4 s2 = s4p[2 * 16 + sub];
            float4 s3 = s4p[3 * 16 + sub];
            float d = e[0].x * s0.x + e[0].y * s0.y + e[0].z * s0.z + e[0].w * s0.w
                    + e[1].x * s1.x + e[1].y * s1.y + e[1].z * s1.z + e[1].w * s1.w
                    + e[2].x * s2.x + e[2].y * s2.y + e[2].z * s2.z + e[2].w * s2.w
                    + e[3].x * s3.x + e[3].y * s3.y + e[3].z * s3.z + e[3].w * s3.w;
            #pragma unroll
            for (int sh = 1; sh < 16; sh <<= 1) d += __shfl_xor(d, sh, 64);
            accs += d;
            acce += __expf(d);
        }
        accs += __shfl_xor(accs, 16, 64);
        accs += __shfl_xor(accs, 32, 64);
        acce += __shfl_xor(acce, 16, 64);
        acce += __shfl_xor(acce, 32, 64);

        // self-term: bf16-rounded ||e||^2 (matches the MFMA diagonal)
        float sd = 0.f;
        #pragma unroll
        for (int p = 0; p < 4; ++p) {
            float c0 = bf2f(f2bf(e[p].x)), c1 = bf2f(f2bf(e[p].y));
            float c2 = bf2f(f2bf(e[p].z)), c3 = bf2f(f2bf(e[p].w));
            sd += c0 * c0 + c1 * c1 + c2 * c2 + c3 * c3;
        }
        #pragma unroll
        for (int sh = 1; sh < 16; sh <<= 1) sd += __shfl_xor(sd, sh, 64);

        if (lane == 0) {
            acce -= __expf(sd);
            accs -= (float)labels[i] * sd;
            atomicAdd(&acc_num[i], accs);
            atomicAdd(&acc_den[i], acce);
        }
    }
}

// ---- final: per-row loss + scalar reduce ----
__global__ __launch_bounds__(256) void final_kernel(
    const int* __restrict__ labels, const float* __restrict__ acc_den,
    const float* __restrict__ acc_num, float* __restrict__ out)
{
    __shared__ int   ibuf[256];
    __shared__ float sbuf[256];
    int t = threadIdx.x;

    int mt = 0;
    for (int it = 0; it < BTOT / 256; ++it) mt += labels[t + it * 256];
    ibuf[t] = mt; __syncthreads();
    for (int s = 128; s > 0; s >>= 1) { if (t < s) ibuf[t] += ibuf[t + s]; __syncthreads(); }
    int mal_total = ibuf[0];
    float cnt = (float)(mal_total - 1 + SS + KKN);

    float total = 0.f;
    for (int it = 0; it < BTOT / 256; ++it) {
        int i = t + it * 256;
        if (labels[i]) total += -acc_num[i] / cnt + __logf(acc_den[i]);
    }
    sbuf[t] = total; __syncthreads();
    for (int s = 128; s > 0; s >>= 1) { if (t < s) sbuf[t] += sbuf[t + s]; __syncthreads(); }
    if (t == 0) out[0] = sbuf[0] / (float)BTOT;
}

extern "C" void kernel_launch(void* const* d_in, const int* in_sizes, int n_in,
                              void* d_out, int out_size, void* d_ws, size_t ws_size,
                              hipStream_t stream) {
    const float* E   = (const float*)d_in[0];
    const float* Sim = (const float*)d_in[1];
    const float* Div = (const float*)d_in[2];
    const int* labels = (const int*)d_in[3];
    float* out = (float*)d_out;

    u16*   ebf     = (u16*)d_ws;
    float* acc_den = (float*)((char*)d_ws + (size_t)BTOT * DD * sizeof(u16));
    float* acc_num = acc_den + BTOT;

    hipMemsetAsync(acc_den, 0, 2 * BTOT * sizeof(float), stream);
    cast_kernel<<<BTOT * DD / 8 / 256, 256, 0, stream>>>(E, ebf);
    fat_kernel<<<2048, 256, 0, stream>>>(E, Sim, Div, ebf, labels, acc_den, acc_num);
    final_kernel<<<1, 256, 0, stream>>>(labels, acc_den, acc_num, out);
}

// Round 4
// 78.548 us; speedup vs baseline: 1.1473x; 1.0696x over previous
//
#include <hip/hip_runtime.h>
#include <stdint.h>

#define BTOT 4096
#define DD   256
#define SS   32
#define KKN  32

typedef unsigned short u16;
using f32x4  = __attribute__((ext_vector_type(4))) float;
using bf16x8 = __attribute__((ext_vector_type(8))) short;

__device__ __forceinline__ u16 f2bf(float f) {
    uint32_t u = __builtin_bit_cast(uint32_t, f);
    u = (u + 0x7FFFu + ((u >> 16) & 1u)) >> 16;
    return (u16)u;
}
__device__ __forceinline__ float bf2f(u16 h) {
    uint32_t u = ((uint32_t)h) << 16;
    return __builtin_bit_cast(float, u);
}

// ---- kernel 0: cast embeddings fp32 -> bf16 ----
__global__ __launch_bounds__(256) void cast_kernel(const float* __restrict__ E,
                                                   u16* __restrict__ ebf) {
    int idx = blockIdx.x * 256 + threadIdx.x;
    const float4* p = reinterpret_cast<const float4*>(E) + (size_t)idx * 2;
    float4 a = p[0], b = p[1];
    uint4 o;
    o.x = (uint32_t)f2bf(a.x) | ((uint32_t)f2bf(a.y) << 16);
    o.y = (uint32_t)f2bf(a.z) | ((uint32_t)f2bf(a.w) << 16);
    o.z = (uint32_t)f2bf(b.x) | ((uint32_t)f2bf(b.y) << 16);
    o.w = (uint32_t)f2bf(b.z) | ((uint32_t)f2bf(b.w) << 16);
    reinterpret_cast<uint4*>(ebf)[idx] = o;
}

// ---- kernel 1: symmetric E@E^T, upper-triangular tiles only ----
// Off-diagonal tiles emit BOTH row-sum partials (strip C) and col-sum
// partials (strip R). Half-partials from the two waves sharing a slot are
// combined through LDS; every gden/gnum slot then has a unique writer.
__global__ __launch_bounds__(256) void gemm_kernel(
    const u16* __restrict__ ebf, const int* __restrict__ labels,
    float* __restrict__ gden, float* __restrict__ gnum)
{
    __shared__ u16 As[128 * 32];
    __shared__ u16 Bs[128 * 32];
    __shared__ float rbuf[2][2][128];   // [pe/pn][wc][row-local]
    __shared__ float cbuf[2][2][128];   // [pe/pn][wr][col-local]

    int bid = blockIdx.x;
    // triangular index -> (R, C), C >= R, 32 strips
    int R = (int)((65.0f - sqrtf(4225.0f - 8.0f * (float)bid)) * 0.5f);
    while (R > 0 && R * (65 - R) / 2 > bid) --R;
    while ((R + 1) * (64 - R) / 2 <= bid) ++R;
    int C = R + (bid - R * (65 - R) / 2);

    int brow = R * 128, bcol = C * 128;
    int t = threadIdx.x, w = t >> 6, lane = t & 63;
    int wr = w >> 1, wc = w & 1;
    int r16 = lane & 15, hi = lane >> 4;
    int kq = hi * 8;

    f32x4 acc[4][4] = {};

    for (int kt = 0; kt < DD / 32; ++kt) {
        int k0 = kt * 32;
        #pragma unroll
        for (int it = 0; it < 2; ++it) {
            int c   = t + 256 * it;
            int row = c >> 2;
            int col = (c & 3) * 8;
            const u16* ga = &ebf[(size_t)(brow + row) * DD + k0 + col];
            const u16* gb = &ebf[(size_t)(bcol + row) * DD + k0 + col];
            __builtin_amdgcn_global_load_lds(
                (const __attribute__((address_space(1))) unsigned int*)ga,
                (__attribute__((address_space(3))) unsigned int*)&As[c * 8], 16, 0, 0);
            __builtin_amdgcn_global_load_lds(
                (const __attribute__((address_space(1))) unsigned int*)gb,
                (__attribute__((address_space(3))) unsigned int*)&Bs[c * 8], 16, 0, 0);
        }
        __syncthreads();

        bf16x8 af[4], bfr[4];
        #pragma unroll
        for (int m = 0; m < 4; ++m)
            af[m] = *(const bf16x8*)&As[(wr * 64 + m * 16 + r16) * 32 + kq];
        #pragma unroll
        for (int n = 0; n < 4; ++n)
            bfr[n] = *(const bf16x8*)&Bs[(wc * 64 + n * 16 + r16) * 32 + kq];
        #pragma unroll
        for (int m = 0; m < 4; ++m)
            #pragma unroll
            for (int n = 0; n < 4; ++n)
                acc[m][n] = __builtin_amdgcn_mfma_f32_16x16x32_bf16(af[m], bfr[n], acc[m][n], 0, 0, 0);
        __syncthreads();
    }

    bool offdiag = (C != R);

    float malf[4];
    #pragma unroll
    for (int n = 0; n < 4; ++n)
        malf[n] = (float)labels[bcol + wc * 64 + n * 16 + r16];
    float malr[16];
    #pragma unroll
    for (int m = 0; m < 4; ++m)
        #pragma unroll
        for (int r = 0; r < 4; ++r)
            malr[m * 4 + r] = (float)labels[brow + wr * 64 + m * 16 + hi * 4 + r];

    float cd[4] = {0.f, 0.f, 0.f, 0.f}, cn[4] = {0.f, 0.f, 0.f, 0.f};

    // row partials (this wave's 64 rows x its 64-col strip) -> rbuf[.][wc][.]
    #pragma unroll
    for (int m = 0; m < 4; ++m) {
        #pragma unroll
        for (int r = 0; r < 4; ++r) {
            float pe = 0.f, pn = 0.f;
            #pragma unroll
            for (int n = 0; n < 4; ++n) {
                float v  = acc[m][n][r];
                float ex = __expf(v);
                pe += ex;
                pn += malf[n] * v;
                cd[n] += ex;
                cn[n] += malr[m * 4 + r] * v;
            }
            #pragma unroll
            for (int s = 1; s < 16; s <<= 1) {
                pe += __shfl_xor(pe, s, 64);
                pn += __shfl_xor(pn, s, 64);
            }
            if (r16 == 0) {
                int rl = wr * 64 + m * 16 + hi * 4 + r;
                rbuf[0][wc][rl] = pe;
                rbuf[1][wc][rl] = pn;
            }
        }
    }

    // col partials (this wave's 64 cols x its 64-row strip) -> cbuf[.][wr][.]
    if (offdiag) {
        #pragma unroll
        for (int n = 0; n < 4; ++n) {
            cd[n] += __shfl_xor(cd[n], 16, 64);
            cd[n] += __shfl_xor(cd[n], 32, 64);
            cn[n] += __shfl_xor(cn[n], 16, 64);
            cn[n] += __shfl_xor(cn[n], 32, 64);
            if (lane < 16) {
                int cl = wc * 64 + n * 16 + lane;
                cbuf[0][wr][cl] = cd[n];
                cbuf[1][wr][cl] = cn[n];
            }
        }
    }
    __syncthreads();

    if (t < 128) {
        int i = brow + t;
        gden[(size_t)i * 32 + C] = rbuf[0][0][t] + rbuf[0][1][t];
        gnum[(size_t)i * 32 + C] = rbuf[1][0][t] + rbuf[1][1][t];
    } else if (offdiag) {
        int tt = t - 128;
        int j = bcol + tt;
        gden[(size_t)j * 32 + R] = cbuf[0][0][tt] + cbuf[0][1][tt];
        gnum[(size_t)j * 32 + R] = cbuf[1][0][tt] + cbuf[1][1][tt];
    }
}

// ---- kernel 2: simdiv, bulk LDS staging + counted-vmcnt consume ----
__global__ __launch_bounds__(256) void simdiv_kernel(
    const float* __restrict__ E, const float* __restrict__ Sim, const float* __restrict__ Div,
    const int* __restrict__ labels, float* __restrict__ sdden, float* __restrict__ sdnum)
{
    extern __shared__ float lds[];   // 64 * 256 floats = 64 KB
    int i = blockIdx.x;
    int t = threadIdx.x, w = t >> 6, lane = t & 63;
    int g = lane >> 4, sub = lane & 15;

    const float4* E4 = reinterpret_cast<const float4*>(E + (size_t)i * DD);
    float4 e0 = E4[0 * 16 + sub], e1 = E4[1 * 16 + sub];
    float4 e2 = E4[2 * 16 + sub], e3 = E4[3 * 16 + sub];

    // stage: wave w owns vectors v = w*16 + vt (fire-and-forget, 16 KB in flight)
    #pragma unroll
    for (int vt = 0; vt < 16; ++vt) {
        int v = w * 16 + vt;
        const float* src = (v < SS) ? (Sim + ((size_t)i * SS + v) * DD)
                                    : (Div + ((size_t)i * KKN + (v - SS)) * DD);
        __builtin_amdgcn_global_load_lds(
            (const __attribute__((address_space(1))) unsigned int*)(src + lane * 4),
            (__attribute__((address_space(3))) unsigned int*)(lds + (size_t)v * DD), 16, 0, 0);
    }

    float accs = 0.f, acce = 0.f;

#define SD_STEP(VT, CNT)                                                          \
    {                                                                             \
        asm volatile("s_waitcnt vmcnt(" #CNT ")" ::: "memory");                   \
        int v = w * 16 + (VT) * 4 + g;                                            \
        const float4* row = reinterpret_cast<const float4*>(lds + (size_t)v * DD);\
        float4 s0 = row[0 * 16 + sub], s1 = row[1 * 16 + sub];                    \
        float4 s2 = row[2 * 16 + sub], s3 = row[3 * 16 + sub];                    \
        float d = e0.x * s0.x + e0.y * s0.y + e0.z * s0.z + e0.w * s0.w           \
                + e1.x * s1.x + e1.y * s1.y + e1.z * s1.z + e1.w * s1.w           \
                + e2.x * s2.x + e2.y * s2.y + e2.z * s2.z + e2.w * s2.w           \
                + e3.x * s3.x + e3.y * s3.y + e3.z * s3.z + e3.w * s3.w;          \
        d += __shfl_xor(d, 1, 64);                                                \
        d += __shfl_xor(d, 2, 64);                                                \
        d += __shfl_xor(d, 4, 64);                                                \
        d += __shfl_xor(d, 8, 64);                                                \
        accs += d;                                                                \
        acce += __expf(d);                                                        \
    }

    SD_STEP(0, 12)
    SD_STEP(1, 8)
    SD_STEP(2, 4)
    SD_STEP(3, 0)
#undef SD_STEP

    accs += __shfl_xor(accs, 16, 64);
    accs += __shfl_xor(accs, 32, 64);
    acce += __shfl_xor(acce, 16, 64);
    acce += __shfl_xor(acce, 32, 64);

    // self-term: bf16-rounded ||e||^2 (matches MFMA diagonal)
    float sd = 0.f;
    {
        float c;
        c = bf2f(f2bf(e0.x)); sd += c * c;  c = bf2f(f2bf(e0.y)); sd += c * c;
        c = bf2f(f2bf(e0.z)); sd += c * c;  c = bf2f(f2bf(e0.w)); sd += c * c;
        c = bf2f(f2bf(e1.x)); sd += c * c;  c = bf2f(f2bf(e1.y)); sd += c * c;
        c = bf2f(f2bf(e1.z)); sd += c * c;  c = bf2f(f2bf(e1.w)); sd += c * c;
        c = bf2f(f2bf(e2.x)); sd += c * c;  c = bf2f(f2bf(e2.y)); sd += c * c;
        c = bf2f(f2bf(e2.z)); sd += c * c;  c = bf2f(f2bf(e2.w)); sd += c * c;
        c = bf2f(f2bf(e3.x)); sd += c * c;  c = bf2f(f2bf(e3.y)); sd += c * c;
        c = bf2f(f2bf(e3.z)); sd += c * c;  c = bf2f(f2bf(e3.w)); sd += c * c;
    }
    sd += __shfl_xor(sd, 1, 64);
    sd += __shfl_xor(sd, 2, 64);
    sd += __shfl_xor(sd, 4, 64);
    sd += __shfl_xor(sd, 8, 64);

    if (lane == 0) {
        float addn = accs, addd = acce;
        if (w == 0) {
            addd -= __expf(sd);
            addn -= (float)labels[i] * sd;
        }
        atomicAdd(&sdnum[i], addn);
        atomicAdd(&sdden[i], addd);
    }
}

// ---- kernel 3: per-row fold (33 partials) + per-block loss partials ----
__global__ __launch_bounds__(128) void reduce1_kernel(
    const int* __restrict__ labels, const float* __restrict__ gden,
    const float* __restrict__ gnum, const float* __restrict__ sdden,
    const float* __restrict__ sdnum, float* __restrict__ part)
{
    __shared__ float sA[128], sB[128];
    __shared__ int   sC[128];
    int p = blockIdx.x, t = threadIdx.x;
    int i = p * 128 + t;

    const float4* dr = reinterpret_cast<const float4*>(gden + (size_t)i * 32);
    const float4* nr = reinterpret_cast<const float4*>(gnum + (size_t)i * 32);
    float den = sdden[i], num = sdnum[i];
    #pragma unroll
    for (int c = 0; c < 8; ++c) {
        float4 a = dr[c]; den += a.x + a.y + a.z + a.w;
        float4 b = nr[c]; num += b.x + b.y + b.z + b.w;
    }
    int lab = labels[i];
    sA[t] = lab ? __logf(den) : 0.f;
    sB[t] = lab ? num : 0.f;
    sC[t] = lab;
    __syncthreads();
    for (int s = 64; s > 0; s >>= 1) {
        if (t < s) { sA[t] += sA[t + s]; sB[t] += sB[t + s]; sC[t] += sC[t + s]; }
        __syncthreads();
    }
    if (t == 0) {
        part[p]      = sA[0];
        part[32 + p] = sB[0];
        part[64 + p] = (float)sC[0];
    }
}

// ---- kernel 4: final scalar combine ----
__global__ __launch_bounds__(64) void final_kernel(const float* __restrict__ part,
                                                   float* __restrict__ out)
{
    int lane = threadIdx.x;
    float lg = (lane < 32) ? part[lane]      : 0.f;
    float nm = (lane < 32) ? part[32 + lane] : 0.f;
    float ml = (lane < 32) ? part[64 + lane] : 0.f;
    #pragma unroll
    for (int s = 1; s < 64; s <<= 1) {
        lg += __shfl_xor(lg, s, 64);
        nm += __shfl_xor(nm, s, 64);
        ml += __shfl_xor(ml, s, 64);
    }
    if (lane == 0) {
        float cnt = ml - 1.f + (float)(SS + KKN);
        out[0] = (lg - nm / cnt) / (float)BTOT;
    }
}

extern "C" void kernel_launch(void* const* d_in, const int* in_sizes, int n_in,
                              void* d_out, int out_size, void* d_ws, size_t ws_size,
                              hipStream_t stream) {
    const float* E   = (const float*)d_in[0];
    const float* Sim = (const float*)d_in[1];
    const float* Div = (const float*)d_in[2];
    const int* labels = (const int*)d_in[3];
    float* out = (float*)d_out;

    char* ws = (char*)d_ws;
    u16*   ebf   = (u16*)ws;                              ws += (size_t)BTOT * DD * sizeof(u16);
    float* gden  = (float*)ws;                            ws += (size_t)BTOT * 32 * sizeof(float);
    float* gnum  = (float*)ws;                            ws += (size_t)BTOT * 32 * sizeof(float);
    float* sdden = (float*)ws;                            ws += BTOT * sizeof(float);
    float* sdnum = (float*)ws;                            ws += BTOT * sizeof(float);
    float* part  = (float*)ws;

    hipMemsetAsync(sdden, 0, 2 * BTOT * sizeof(float), stream);
    cast_kernel<<<BTOT * DD / 8 / 256, 256, 0, stream>>>(E, ebf);
    gemm_kernel<<<528, 256, 0, stream>>>(ebf, labels, gden, gnum);
    simdiv_kernel<<<BTOT, 256, 64 * 1024, stream>>>(E, Sim, Div, labels, sdden, sdnum);
    reduce1_kernel<<<32, 128, 0, stream>>>(labels, gden, gnum, sdden, sdnum, part);
    final_kernel<<<1, 64, 0, stream>>>(part, out);
}